// Round 19
// baseline (222.369 us; speedup 1.0000x reference)
//
#include <hip/hip_runtime.h>

// ---------- common ----------
typedef short sh8 __attribute__((ext_vector_type(8)));
typedef float f32x4 __attribute__((ext_vector_type(4)));

#define DEV __device__ __forceinline__

DEV f32x4 mfma16(sh8 a, sh8 b, f32x4 c) {
  return __builtin_amdgcn_mfma_f32_16x16x32_bf16(a, b, c, 0, 0, 0);
}

DEV unsigned short f2bf(float f) {
  unsigned u = __float_as_uint(f);
  u = u + 0x7FFFu + ((u >> 16) & 1u);   // RNE
  return (unsigned short)(u >> 16);
}

DEV unsigned cvtpk(float lo, float hi) {
  unsigned r;
  asm("v_cvt_pk_bf16_f32 %0, %1, %2" : "=v"(r) : "v"(lo), "v"(hi));
  return r;
}

DEV void gll16(const void* g, void* l) {
  __builtin_amdgcn_global_load_lds(
      (const __attribute__((address_space(1))) unsigned int*)g,
      (__attribute__((address_space(3))) unsigned int*)l, 16, 0, 0);
}

// ---------- kernel: x fp32 -> bf16 ----------
__global__ void cvt_x_kernel(const float* __restrict__ x, unsigned short* __restrict__ xb, int n4) {
  int i = blockIdx.x * blockDim.x + threadIdx.x;
  int stride = gridDim.x * blockDim.x;
  for (; i < n4; i += stride) {
    float4 v = ((const float4*)x)[i];
    ushort4 o;
    o.x = f2bf(v.x); o.y = f2bf(v.y); o.z = f2bf(v.z); o.w = f2bf(v.w);
    ((ushort4*)xb)[i] = o;
  }
}

// ---------- kernel: weight transpose + cvt ----------
__global__ void cvt_wT_kernel(const float* __restrict__ W0, const float* __restrict__ W1,
                              const float* __restrict__ W2, const float* __restrict__ W3,
                              unsigned short* __restrict__ T0, unsigned short* __restrict__ T1,
                              unsigned short* __restrict__ T2, unsigned short* __restrict__ T3) {
  const float* W; unsigned short* T;
  switch (blockIdx.z) {
    case 0: W = W0; T = T0; break;
    case 1: W = W1; T = T1; break;
    case 2: W = W2; T = T2; break;
    default: W = W3; T = T3; break;
  }
  __shared__ float tile[32][33];
  int tx = threadIdx.x & 31, ty = threadIdx.x >> 5;
  int r0 = blockIdx.y * 32, c0 = blockIdx.x * 32;
#pragma unroll
  for (int i = 0; i < 4; i++) tile[ty + i * 8][tx] = W[(r0 + ty + i * 8) * 512 + c0 + tx];
  __syncthreads();
#pragma unroll
  for (int i = 0; i < 4; i++) T[(c0 + ty + i * 8) * 512 + r0 + tx] = f2bf(tile[tx][ty + i * 8]);
}

// ================= 256x256 U-GEMM, 4-phase, 2 barriers/K-tile, no setprio ==========
// r13 wait coverage (VM2@ph1 covers K1(t); VM2@ph4 covers Q0,Q1,K0(t+1)).
// STG issued BEFORE the ds_read cluster each phase (earlier VMEM flight).
// XCD decode: 2D-chunked (each XCD owns a 16x8 tile rectangle).
__global__ __launch_bounds__(512, 2) void gemm256_u_kernel(
    const unsigned short* __restrict__ Q, const unsigned short* __restrict__ Kb,
    unsigned short* __restrict__ U, float* __restrict__ lpart) {
  __shared__ __align__(16) unsigned short smem[65536];
  const int tid = threadIdx.x, lane = tid & 63;
  const int w = tid >> 6;
  const int g = lane >> 4, r = lane & 15;
  const int wm2 = w & 1, wn4 = w >> 1;
  const int xcd = blockIdx.x & 7, j = blockIdx.x >> 3;           // XCD = bid%8
  const int brow = ((xcd & 1) * 16 + (j & 15)) * 256;            // q base
  const int bcol = ((xcd >> 1) * 8 + (j >> 4)) * 256;            // k base
  const int srow = tid >> 3;
  const int sg = tid & 7;

  f32x4 acc[2][2][4][2] = {};           // [kh][qh][m][n]

#define STG(b, a, h, kt)                                                                       \
  do {                                                                                         \
    const unsigned short* _src = (a) ? Kb : Q;                                                 \
    int _base = (a) ? bcol : brow;                                                             \
    int _r0 = (h) * 128 + srow;                                                                \
    int _r1 = _r0 + 64;                                                                        \
    unsigned short* _d = smem + (b) * 32768 + (a) * 16384 + (h) * 8192 + tid * 8;              \
    gll16(_src + (size_t)(_base + _r0) * 512 + (kt) * 64 + ((sg ^ (_r0 & 7)) * 8), _d);        \
    gll16(_src + (size_t)(_base + _r1) * 512 + (kt) * 64 + ((sg ^ (_r1 & 7)) * 8), _d + 4096); \
  } while (0)

  auto LDK = [&](sh8 (&kf)[2][4], int B_, int kh) {
    const unsigned short* Bs = smem + B_ * 32768 + 16384;
#pragma unroll
    for (int kk = 0; kk < 2; kk++)
#pragma unroll
      for (int m = 0; m < 4; m++) {
        int row = kh * 128 + wm2 * 64 + m * 16 + r;
        kf[kk][m] = *(const sh8*)&Bs[row * 64 + (((kk * 4 + g) ^ (r & 7)) * 8)];
      }
  };
  auto LDQ = [&](sh8 (&qf)[2][2], int B_, int qh) {
    const unsigned short* As = smem + B_ * 32768;
#pragma unroll
    for (int kk = 0; kk < 2; kk++)
#pragma unroll
      for (int n = 0; n < 2; n++) {
        int row = qh * 128 + wn4 * 32 + n * 16 + r;
        qf[kk][n] = *(const sh8*)&As[row * 64 + (((kk * 4 + g) ^ (r & 7)) * 8)];
      }
  };
  auto MM = [&](f32x4 (&c)[4][2], sh8 (&kf)[2][4], sh8 (&qf)[2][2]) {
#pragma unroll
    for (int kk = 0; kk < 2; kk++)
#pragma unroll
      for (int m = 0; m < 4; m++)
#pragma unroll
        for (int n = 0; n < 2; n++)
          c[m][n] = mfma16(kf[kk][m], qf[kk][n], c[m][n]);
  };
#define BAR asm volatile("s_barrier" ::: "memory")
#define VM2 asm volatile("s_waitcnt vmcnt(2)" ::: "memory")

  STG(0, 0, 0, 0); STG(0, 0, 1, 0); STG(0, 1, 0, 0); STG(0, 1, 1, 0);
  asm volatile("s_waitcnt vmcnt(0)" ::: "memory");
  BAR;

#pragma unroll
  for (int kt = 0; kt < 8; ++kt) {
    const int cur = kt & 1, nb = cur ^ 1;
    const int kn = (kt < 7) ? kt + 1 : 7;   // tail: redundant restage keeps counts uniform
    sh8 k0[2][4], k1[2][4], q0[2][2], q1[2][2];
    // ph1 (publishing barrier: K1(t) via VM2)
    STG(nb, 0, 0, kn);
    LDK(k0, cur, 0); LDQ(q0, cur, 0);
    VM2; BAR;
    MM(acc[0][0], k0, q0);
    // ph2 (no barrier)
    STG(nb, 0, 1, kn);
    LDQ(q1, cur, 1);
    MM(acc[0][1], k0, q1);
    // ph3 (no barrier)
    STG(nb, 1, 0, kn);
    LDK(k1, cur, 1);
    MM(acc[1][0], k1, q0);
    // ph4 (publishing barrier: Q0,Q1,K0(t+1) via VM2)
    STG(nb, 1, 1, kn);
    VM2; BAR;
    MM(acc[1][1], k1, q1);
  }
#undef STG

  asm volatile("s_waitcnt vmcnt(0)" ::: "memory");
  __syncthreads();

  const float K2c = 0.04419417382415922f * 1.4426950408889634f;  // 1/sqrt(512)*log2e
#pragma unroll
  for (int qh = 0; qh < 2; qh++)
#pragma unroll
    for (int n = 0; n < 2; n++) {
      int qr = qh * 128 + wn4 * 32 + n * 16 + r;
      float s = 0.f;
#pragma unroll
      for (int kh = 0; kh < 2; kh++)
#pragma unroll
        for (int m = 0; m < 4; m++) {
          f32x4 a = acc[kh][qh][m][n];
          float v0 = __builtin_amdgcn_exp2f(a[0] * K2c);
          float v1 = __builtin_amdgcn_exp2f(a[1] * K2c);
          float v2 = __builtin_amdgcn_exp2f(a[2] * K2c);
          float v3 = __builtin_amdgcn_exp2f(a[3] * K2c);
          s += (v0 + v1) + (v2 + v3);
          uint2 pk; pk.x = cvtpk(v0, v1); pk.y = cvtpk(v2, v3);
          int ke = kh * 128 + wm2 * 64 + m * 16 + g * 4;
          int el = qr * 256 + (ke ^ ((qr & 7) * 8));
          *(uint2*)&smem[el] = pk;
        }
      s += __shfl_xor(s, 16);
      s += __shfl_xor(s, 32);
      if (g == 0)
        lpart[(size_t)((bcol >> 7) + wm2) * 8192 + brow + qr] = s;
    }
  __syncthreads();
#pragma unroll
  for (int jj = 0; jj < 16; jj++) {
    int row = jj * 16 + (tid >> 5);
    int g32 = tid & 31;
    uint4 v = *(const uint4*)&smem[row * 256 + ((g32 ^ (row & 7)) * 8)];
    *(uint4*)&U[(size_t)(brow + row) * 8192 + bcol + g32 * 8] = v;
  }
}

// ================= 256x256 PV-GEMM, same structure, split-K=4, bf16 partials ========
__global__ __launch_bounds__(512, 2) void gemm256_pv_kernel(
    const unsigned short* __restrict__ Uu, const unsigned short* __restrict__ VT,
    unsigned short* __restrict__ P0, unsigned short* __restrict__ P1,
    unsigned short* __restrict__ P2, unsigned short* __restrict__ P3) {
  __shared__ __align__(16) unsigned short smem[65536];
  const int tid = threadIdx.x, lane = tid & 63;
  const int w = tid >> 6;
  const int g = lane >> 4, r = lane & 15;
  const int wm2 = w & 1, wn4 = w >> 1;
  const int c = blockIdx.x & 7;
  const int hi = blockIdx.x >> 3;
  const int nt = hi & 1, qthi = hi >> 1;
  const int qlo = c >> 2, kz = c & 3;
  const int qt = qthi * 2 + qlo;
  const int brow = qt * 256;
  const int bcol = nt * 256;
  const int koff = kz * 2048;
  const int srow = tid >> 3;
  const int sg = tid & 7;
  unsigned short* P = (kz == 0) ? P0 : (kz == 1) ? P1 : (kz == 2) ? P2 : P3;

  f32x4 acc[2][2][4][2] = {};             // [dh][qh][m][n]

#define STGP(b, a, h, kt)                                                                        \
  do {                                                                                           \
    const unsigned short* _src = (a) ? VT : Uu;                                                  \
    int _base = (a) ? bcol : brow;                                                               \
    int _r0 = (h) * 128 + srow;                                                                  \
    int _r1 = _r0 + 64;                                                                          \
    unsigned short* _d = smem + (b) * 32768 + (a) * 16384 + (h) * 8192 + tid * 8;                \
    gll16(_src + (size_t)(_base + _r0) * 8192 + koff + (kt) * 64 + ((sg ^ (_r0 & 7)) * 8), _d);  \
    gll16(_src + (size_t)(_base + _r1) * 8192 + koff + (kt) * 64 + ((sg ^ (_r1 & 7)) * 8),       \
          _d + 4096);                                                                            \
  } while (0)

  auto LDV = [&](sh8 (&vf)[2][4], int B_, int dh) {
    const unsigned short* Bs = smem + B_ * 32768 + 16384;
#pragma unroll
    for (int kk = 0; kk < 2; kk++)
#pragma unroll
      for (int m = 0; m < 4; m++) {
        int row = dh * 128 + wm2 * 64 + m * 16 + r;
        vf[kk][m] = *(const sh8*)&Bs[row * 64 + (((kk * 4 + g) ^ (r & 7)) * 8)];
      }
  };
  auto LDU = [&](sh8 (&uf)[2][2], int B_, int qh) {
    const unsigned short* As = smem + B_ * 32768;
#pragma unroll
    for (int kk = 0; kk < 2; kk++)
#pragma unroll
      for (int n = 0; n < 2; n++) {
        int row = qh * 128 + wn4 * 32 + n * 16 + r;
        uf[kk][n] = *(const sh8*)&As[row * 64 + (((kk * 4 + g) ^ (r & 7)) * 8)];
      }
  };
  auto MM = [&](f32x4 (&cc)[4][2], sh8 (&vf)[2][4], sh8 (&uf)[2][2]) {
#pragma unroll
    for (int kk = 0; kk < 2; kk++)
#pragma unroll
      for (int m = 0; m < 4; m++)
#pragma unroll
        for (int n = 0; n < 2; n++)
          cc[m][n] = mfma16(vf[kk][m], uf[kk][n], cc[m][n]);
  };

  STGP(0, 0, 0, 0); STGP(0, 0, 1, 0); STGP(0, 1, 0, 0); STGP(0, 1, 1, 0);
  asm volatile("s_waitcnt vmcnt(0)" ::: "memory");
  BAR;

#pragma unroll 2
  for (int kt = 0; kt < 32; ++kt) {
    const int cur = kt & 1, nb = cur ^ 1;
    const int kn = (kt < 31) ? kt + 1 : 31;
    sh8 v0[2][4], v1[2][4], u0[2][2], u1[2][2];
    // ph1 (publishing barrier)
    STGP(nb, 0, 0, kn);
    LDV(v0, cur, 0); LDU(u0, cur, 0);
    VM2; BAR;
    MM(acc[0][0], v0, u0);
    // ph2 (no barrier)
    STGP(nb, 0, 1, kn);
    LDU(u1, cur, 1);
    MM(acc[0][1], v0, u1);
    // ph3 (no barrier)
    STGP(nb, 1, 0, kn);
    LDV(v1, cur, 1);
    MM(acc[1][0], v1, u0);
    // ph4 (publishing barrier)
    STGP(nb, 1, 1, kn);
    VM2; BAR;
    MM(acc[1][1], v1, u1);
  }
#undef STGP
#undef BAR
#undef VM2

  asm volatile("s_waitcnt vmcnt(0)" ::: "memory");
  __syncthreads();

  // epilogue: bf16 restage (swizzled) + coalesced 512B-row stores to partial
#pragma unroll
  for (int qh = 0; qh < 2; qh++)
#pragma unroll
    for (int n = 0; n < 2; n++) {
      int qr = qh * 128 + wn4 * 32 + n * 16 + r;
#pragma unroll
      for (int dh = 0; dh < 2; dh++)
#pragma unroll
        for (int m = 0; m < 4; m++) {
          f32x4 a = acc[dh][qh][m][n];
          uint2 pk; pk.x = cvtpk(a[0], a[1]); pk.y = cvtpk(a[2], a[3]);
          int de = dh * 128 + wm2 * 64 + m * 16 + g * 4;
          int el = qr * 256 + (de ^ ((qr & 7) * 8));
          *(uint2*)&smem[el] = pk;
        }
    }
  __syncthreads();
#pragma unroll
  for (int jj = 0; jj < 16; jj++) {
    int row = jj * 16 + (tid >> 5);
    int g32 = tid & 31;
    uint4 v = *(const uint4*)&smem[row * 256 + ((g32 ^ (row & 7)) * 8)];
    *(uint4*)&P[(size_t)(brow + row) * 512 + bcol + g32 * 8] = v;
  }
}

// ---------- 128x128 GEMM core (BK=64, dbuf + counted vmcnt) ----------
template <int MODE>
DEV void gemm_core(const unsigned short* __restrict__ A, int lda,
                   const unsigned short* __restrict__ Bt, int ldb,
                   const float* __restrict__ bias, void* __restrict__ Cv, int ldc,
                   int kSteps, int koff, int brow, int bcol,
                   unsigned short* smem, bool transp) {
  const int tid = threadIdx.x, lane = tid & 63, w = tid >> 6;
  const int g = lane >> 4, r = lane & 15;
  const int wr = w >> 1, wc = w & 1;
  const int rA = w * 8 + (lane >> 3);
  const int sgl = lane & 7;
  const int scol = ((sgl ^ (lane >> 3)) * 8);
  const unsigned short* aP = A + (size_t)(brow + rA) * lda + koff + scol;
  const unsigned short* bP = Bt + (size_t)(bcol + rA) * ldb + koff + scol;
  const int lOff = rA * 64 + sgl * 8;
  f32x4 acc[4][4] = {};
  const int fr = r & 7;

  auto STAGE = [&](int buf, int ks) {
    unsigned short* lA = smem + buf * 16384 + lOff;
    unsigned short* lB = smem + buf * 16384 + 8192 + lOff;
    const size_t ko = (size_t)ks * 64;
#pragma unroll
    for (int cc = 0; cc < 4; cc++) gll16(aP + (size_t)cc * 32 * lda + ko, lA + cc * 32 * 64);
#pragma unroll
    for (int cc = 0; cc < 4; cc++) gll16(bP + (size_t)cc * 32 * ldb + ko, lB + cc * 32 * 64);
  };
  auto COMPUTE = [&](int buf) {
    const unsigned short* As = smem + buf * 16384;
    const unsigned short* Bs = As + 8192;
#pragma unroll
    for (int kk = 0; kk < 2; kk++) {
      sh8 af[4], bfr[4];
#pragma unroll
      for (int m = 0; m < 4; m++)
        af[m] = *(const sh8*)&As[(wr * 64 + m * 16 + r) * 64 + (((kk * 4 + g) ^ fr) * 8)];
#pragma unroll
      for (int n = 0; n < 4; n++)
        bfr[n] = *(const sh8*)&Bs[(wc * 64 + n * 16 + r) * 64 + (((kk * 4 + g) ^ fr) * 8)];
#pragma unroll
      for (int m = 0; m < 4; m++)
#pragma unroll
        for (int n = 0; n < 4; n++) acc[m][n] = mfma16(af[m], bfr[n], acc[m][n]);
    }
  };

  STAGE(0, 0);
  int cur = 0;
  for (int ks = 0; ks + 1 < kSteps; ks++) {
    STAGE(cur ^ 1, ks + 1);
    asm volatile("s_waitcnt vmcnt(8)" ::: "memory");
    asm volatile("s_barrier" ::: "memory");
    COMPUTE(cur);
    asm volatile("s_barrier" ::: "memory");
    cur ^= 1;
  }
  asm volatile("s_waitcnt vmcnt(0)" ::: "memory");
  asm volatile("s_barrier" ::: "memory");
  COMPUTE(cur);

  if (MODE == 0) {
#pragma unroll
    for (int n = 0; n < 4; n++) {
      int col = bcol + wc * 64 + n * 16 + r;
      float bv = bias ? bias[col] : 0.f;
#pragma unroll
      for (int m = 0; m < 4; m++) {
        int row = brow + wr * 64 + m * 16 + g * 4;
#pragma unroll
        for (int i = 0; i < 4; i++)
          ((float*)Cv)[(size_t)(row + i) * ldc + col] = acc[m][n][i] + bv;
      }
    }
  } else {
    __syncthreads();
    if (!transp) {
#pragma unroll
      for (int m = 0; m < 4; m++) {
#pragma unroll
        for (int n = 0; n < 4; n++) {
          int coll = wc * 64 + n * 16 + r;
          float bv = bias ? bias[bcol + coll] : 0.f;
          int rb = (wr * 64 + m * 16 + g * 4) * 132 + coll;
          smem[rb] = f2bf(acc[m][n][0] + bv);
          smem[rb + 132] = f2bf(acc[m][n][1] + bv);
          smem[rb + 264] = f2bf(acc[m][n][2] + bv);
          smem[rb + 396] = f2bf(acc[m][n][3] + bv);
        }
      }
      __syncthreads();
      unsigned short* C = (unsigned short*)Cv;
#pragma unroll
      for (int jj = 0; jj < 8; jj++) {
        int row = w * 32 + jj * 4 + (lane >> 4);
        int colb = (lane & 15) * 8;
        uint4 v = *(const uint4*)&smem[row * 132 + colb];
        *(uint4*)&C[(size_t)(brow + row) * ldc + bcol + colb] = v;
      }
    } else {
      // transposed write: smem[col][row], then coalesced rows of C^T
#pragma unroll
      for (int m = 0; m < 4; m++) {
#pragma unroll
        for (int n = 0; n < 4; n++) {
          int coll = wc * 64 + n * 16 + r;
          float bv = bias ? bias[bcol + coll] : 0.f;
          int qrow = wr * 64 + m * 16 + g * 4;
          uint2 pk;
          pk.x = cvtpk(acc[m][n][0] + bv, acc[m][n][1] + bv);
          pk.y = cvtpk(acc[m][n][2] + bv, acc[m][n][3] + bv);
          *(uint2*)&smem[coll * 132 + qrow] = pk;
        }
      }
      __syncthreads();
      unsigned short* C = (unsigned short*)Cv;
#pragma unroll
      for (int jj = 0; jj < 8; jj++) {
        int hrow = w * 32 + jj * 4 + (lane >> 4);
        int nb8 = (lane & 15) * 8;
        uint4 v = *(const uint4*)&smem[hrow * 132 + nb8];
        *(uint4*)&C[(size_t)(bcol + hrow) * ldc + brow + nb8] = v;
      }
    }
  }
}

// ---------- GEMM wrappers ----------
__global__ __launch_bounds__(256, 2) void gemm_qkv_kernel(
    const unsigned short* __restrict__ A,
    const unsigned short* __restrict__ B0, const unsigned short* __restrict__ B1,
    const unsigned short* __restrict__ B2,
    const float* __restrict__ c0, const float* __restrict__ c1, const float* __restrict__ c2,
    unsigned short* __restrict__ C0, unsigned short* __restrict__ C1,
    unsigned short* __restrict__ CT2) {
  __shared__ __align__(16) unsigned short smem[32768];
  const unsigned short* Bt; const float* bias; unsigned short* C;
  bool tr; int ldc;
  switch (blockIdx.z) {
    case 0: Bt = B0; bias = c0; C = C0; tr = false; ldc = 512; break;
    case 1: Bt = B1; bias = c1; C = C1; tr = false; ldc = 512; break;
    default: Bt = B2; bias = c2; C = CT2; tr = true; ldc = 8192; break;  // V -> vtb^T
  }
  gemm_core<1>(A, 512, Bt, 512, bias, C, ldc, 8, 0,
               blockIdx.x * 128, blockIdx.y * 128, smem, tr);
}

__global__ __launch_bounds__(256, 2) void gemm_o_kernel(
    const unsigned short* __restrict__ att, const unsigned short* __restrict__ woT,
    const float* __restrict__ bo, float* __restrict__ out) {
  __shared__ __align__(16) unsigned short smem[32768];
  gemm_core<0>(att, 512, woT, 512, bo, out, 512, 8, 0,
               blockIdx.x * 128, blockIdx.y * 128, smem, false);
}

// ---------- combine row-sum partials (64 k-chunks) -> 1/l ----------
__global__ void combine_l_kernel(const float* __restrict__ lpart, float* __restrict__ linv) {
  int row = blockIdx.x * 256 + threadIdx.x;
  float s = 0.f;
#pragma unroll 8
  for (int j = 0; j < 64; j++) s += lpart[(size_t)j * 8192 + row];
  linv[row] = 1.0f / s;
}

// ---------- add four bf16 partials * linv[row] -> bf16 ----------
__global__ void addcvt4_kernel(const unsigned short* __restrict__ p0,
                               const unsigned short* __restrict__ p1,
                               const unsigned short* __restrict__ p2,
                               const unsigned short* __restrict__ p3,
                               const float* __restrict__ linv,
                               unsigned short* __restrict__ o, int n8) {
  int i = blockIdx.x * blockDim.x + threadIdx.x;
  int stride = gridDim.x * blockDim.x;
  for (; i < n8; i += stride) {
    float inv = linv[i >> 6];
    uint4 a = ((const uint4*)p0)[i];
    uint4 b = ((const uint4*)p1)[i];
    uint4 c = ((const uint4*)p2)[i];
    uint4 d = ((const uint4*)p3)[i];
    const unsigned* ua = (const unsigned*)&a;
    const unsigned* ub = (const unsigned*)&b;
    const unsigned* uc = (const unsigned*)&c;
    const unsigned* ud = (const unsigned*)&d;
    unsigned out[4];
#pragma unroll
    for (int e = 0; e < 4; e++) {
      float lo = __uint_as_float(ua[e] << 16) + __uint_as_float(ub[e] << 16) +
                 __uint_as_float(uc[e] << 16) + __uint_as_float(ud[e] << 16);
      float hi = __uint_as_float(ua[e] & 0xffff0000u) + __uint_as_float(ub[e] & 0xffff0000u) +
                 __uint_as_float(uc[e] & 0xffff0000u) + __uint_as_float(ud[e] & 0xffff0000u);
      out[e] = cvtpk(lo * inv, hi * inv);
    }
    ((uint4*)o)[i] = *(uint4*)out;
  }
}

// ---------- launch ----------
extern "C" void kernel_launch(void* const* d_in, const int* in_sizes, int n_in,
                              void* d_out, int out_size, void* d_ws, size_t ws_size,
                              hipStream_t stream) {
  const float* x  = (const float*)d_in[0];
  const float* Wq = (const float*)d_in[1];
  const float* bq = (const float*)d_in[2];
  const float* Wk = (const float*)d_in[3];
  const float* bk = (const float*)d_in[4];
  const float* Wv = (const float*)d_in[5];
  const float* bv = (const float*)d_in[6];
  const float* Wo = (const float*)d_in[7];
  const float* bo = (const float*)d_in[8];
  char* ws = (char*)d_ws;

  unsigned short* U   = (unsigned short*)(ws + 0);          // 134.2 MB
  unsigned short* xb  = (unsigned short*)(ws + 0);          // overlay (dead after QKV)
  unsigned short* att = (unsigned short*)(ws + 0);          // overlay (after PV)
  unsigned short* qb  = (unsigned short*)(ws + 134217728);
  unsigned short* kb  = (unsigned short*)(ws + 142606336);
  unsigned short* vtb = (unsigned short*)(ws + 150994944);
  unsigned short* wqT = (unsigned short*)(ws + 159383552);
  unsigned short* wkT = (unsigned short*)(ws + 159907840);
  unsigned short* wvT = (unsigned short*)(ws + 160432128);
  unsigned short* woT = (unsigned short*)(ws + 160956416);
  float* lpart = (float*)(ws + 161480704);                  // 2 MB [64][8192]
  float* linv  = (float*)(ws + 165675008);                  // 32 KB
  unsigned short* P0 = qb;
  unsigned short* P1 = kb;
  unsigned short* P2 = (unsigned short*)d_out;
  unsigned short* P3 = (unsigned short*)d_out + 4194304;

  cvt_x_kernel<<<2048, 256, 0, stream>>>(x, xb, 8192 * 512 / 4);
  cvt_wT_kernel<<<dim3(16, 16, 4), 256, 0, stream>>>(Wq, Wk, Wv, Wo, wqT, wkT, wvT, woT);
  gemm_qkv_kernel<<<dim3(64, 4, 3), 256, 0, stream>>>(
      xb, wqT, wkT, wvT, bq, bk, bv, qb, kb, vtb);
  gemm256_u_kernel<<<1024, 512, 0, stream>>>(qb, kb, U, lpart);
  combine_l_kernel<<<32, 256, 0, stream>>>(lpart, linv);
  gemm256_pv_kernel<<<256, 512, 0, stream>>>(U, vtb, P0, P1, P2, P3);
  addcvt4_kernel<<<2048, 256, 0, stream>>>(P0, P1, P2, P3, linv, att, 8192 * 512 / 8);
  gemm_o_kernel<<<dim3(64, 4), 256, 0, stream>>>(att, woT, bo, (float*)d_out);
}

// Round 20
// 198.389 us; speedup vs baseline: 1.1209x; 1.1209x over previous
//
#include <hip/hip_runtime.h>

// ---------- common ----------
typedef short sh8 __attribute__((ext_vector_type(8)));
typedef float f32x4 __attribute__((ext_vector_type(4)));

#define DEV __device__ __forceinline__

DEV f32x4 mfma16(sh8 a, sh8 b, f32x4 c) {
  return __builtin_amdgcn_mfma_f32_16x16x32_bf16(a, b, c, 0, 0, 0);
}

DEV unsigned short f2bf(float f) {
  unsigned u = __float_as_uint(f);
  u = u + 0x7FFFu + ((u >> 16) & 1u);   // RNE
  return (unsigned short)(u >> 16);
}

DEV unsigned cvtpk(float lo, float hi) {
  unsigned r;
  asm("v_cvt_pk_bf16_f32 %0, %1, %2" : "=v"(r) : "v"(lo), "v"(hi));
  return r;
}

DEV void gll16(const void* g, void* l) {
  __builtin_amdgcn_global_load_lds(
      (const __attribute__((address_space(1))) unsigned int*)g,
      (__attribute__((address_space(3))) unsigned int*)l, 16, 0, 0);
}

// ---------- kernel: x fp32 -> bf16 ----------
__global__ void cvt_x_kernel(const float* __restrict__ x, unsigned short* __restrict__ xb, int n4) {
  int i = blockIdx.x * blockDim.x + threadIdx.x;
  int stride = gridDim.x * blockDim.x;
  for (; i < n4; i += stride) {
    float4 v = ((const float4*)x)[i];
    ushort4 o;
    o.x = f2bf(v.x); o.y = f2bf(v.y); o.z = f2bf(v.z); o.w = f2bf(v.w);
    ((ushort4*)xb)[i] = o;
  }
}

// ---------- kernel: weight transpose + cvt ----------
__global__ void cvt_wT_kernel(const float* __restrict__ W0, const float* __restrict__ W1,
                              const float* __restrict__ W2, const float* __restrict__ W3,
                              unsigned short* __restrict__ T0, unsigned short* __restrict__ T1,
                              unsigned short* __restrict__ T2, unsigned short* __restrict__ T3) {
  const float* W; unsigned short* T;
  switch (blockIdx.z) {
    case 0: W = W0; T = T0; break;
    case 1: W = W1; T = T1; break;
    case 2: W = W2; T = T2; break;
    default: W = W3; T = T3; break;
  }
  __shared__ float tile[32][33];
  int tx = threadIdx.x & 31, ty = threadIdx.x >> 5;
  int r0 = blockIdx.y * 32, c0 = blockIdx.x * 32;
#pragma unroll
  for (int i = 0; i < 4; i++) tile[ty + i * 8][tx] = W[(r0 + ty + i * 8) * 512 + c0 + tx];
  __syncthreads();
#pragma unroll
  for (int i = 0; i < 4; i++) T[(c0 + ty + i * 8) * 512 + r0 + tx] = f2bf(tile[tx][ty + i * 8]);
}

// ================= 256x256 U-GEMM, swapped-operand 4-phase (r13 schedule) =================
// VM2 at ph1 (covers K1(t)) and ph4 (covers Q0,Q1,K0(t+1)); one barrier per phase.
// XCD decode: 2D-chunked (each XCD owns a 16x8 tile rectangle).
__global__ __launch_bounds__(512, 2) void gemm256_u_kernel(
    const unsigned short* __restrict__ Q, const unsigned short* __restrict__ Kb,
    unsigned short* __restrict__ U, float* __restrict__ lpart) {
  __shared__ __align__(16) unsigned short smem[65536];
  const int tid = threadIdx.x, lane = tid & 63;
  const int w = tid >> 6;
  const int g = lane >> 4, r = lane & 15;
  const int wm2 = w & 1, wn4 = w >> 1;
  const int xcd = blockIdx.x & 7, j = blockIdx.x >> 3;           // XCD = bid%8
  const int brow = ((xcd & 1) * 16 + (j & 15)) * 256;            // q base
  const int bcol = ((xcd >> 1) * 8 + (j >> 4)) * 256;            // k base
  const int srow = tid >> 3;
  const int sg = tid & 7;

  f32x4 acc[2][2][4][2] = {};           // [kh][qh][m][n]

#define STG(b, a, h, kt)                                                                       \
  do {                                                                                         \
    const unsigned short* _src = (a) ? Kb : Q;                                                 \
    int _base = (a) ? bcol : brow;                                                             \
    int _r0 = (h) * 128 + srow;                                                                \
    int _r1 = _r0 + 64;                                                                        \
    unsigned short* _d = smem + (b) * 32768 + (a) * 16384 + (h) * 8192 + tid * 8;              \
    gll16(_src + (size_t)(_base + _r0) * 512 + (kt) * 64 + ((sg ^ (_r0 & 7)) * 8), _d);        \
    gll16(_src + (size_t)(_base + _r1) * 512 + (kt) * 64 + ((sg ^ (_r1 & 7)) * 8), _d + 4096); \
  } while (0)

  auto LDK = [&](sh8 (&kf)[2][4], int B_, int kh) {
    const unsigned short* Bs = smem + B_ * 32768 + 16384;
#pragma unroll
    for (int kk = 0; kk < 2; kk++)
#pragma unroll
      for (int m = 0; m < 4; m++) {
        int row = kh * 128 + wm2 * 64 + m * 16 + r;
        kf[kk][m] = *(const sh8*)&Bs[row * 64 + (((kk * 4 + g) ^ (r & 7)) * 8)];
      }
  };
  auto LDQ = [&](sh8 (&qf)[2][2], int B_, int qh) {
    const unsigned short* As = smem + B_ * 32768;
#pragma unroll
    for (int kk = 0; kk < 2; kk++)
#pragma unroll
      for (int n = 0; n < 2; n++) {
        int row = qh * 128 + wn4 * 32 + n * 16 + r;
        qf[kk][n] = *(const sh8*)&As[row * 64 + (((kk * 4 + g) ^ (r & 7)) * 8)];
      }
  };
  auto MM = [&](f32x4 (&c)[4][2], sh8 (&kf)[2][4], sh8 (&qf)[2][2]) {
    __builtin_amdgcn_s_setprio(1);
#pragma unroll
    for (int kk = 0; kk < 2; kk++)
#pragma unroll
      for (int m = 0; m < 4; m++)
#pragma unroll
        for (int n = 0; n < 2; n++)
          c[m][n] = mfma16(kf[kk][m], qf[kk][n], c[m][n]);
    __builtin_amdgcn_s_setprio(0);
  };
#define BAR asm volatile("s_barrier" ::: "memory")
#define VM2 asm volatile("s_waitcnt vmcnt(2)" ::: "memory")

  STG(0, 0, 0, 0); STG(0, 0, 1, 0); STG(0, 1, 0, 0); STG(0, 1, 1, 0);
  asm volatile("s_waitcnt vmcnt(0)" ::: "memory");
  BAR;

#pragma unroll
  for (int kt = 0; kt < 8; ++kt) {
    const int cur = kt & 1, nb = cur ^ 1;
    const int kn = (kt < 7) ? kt + 1 : 7;   // tail: redundant restage keeps counts uniform
    sh8 k0[2][4], k1[2][4], q0[2][2], q1[2][2];
    // ph1
    LDK(k0, cur, 0); LDQ(q0, cur, 0);
    STG(nb, 0, 0, kn);
    VM2; BAR;
    MM(acc[0][0], k0, q0);
    // ph2
    LDQ(q1, cur, 1);
    STG(nb, 0, 1, kn);
    BAR;
    MM(acc[0][1], k0, q1);
    // ph3
    LDK(k1, cur, 1);
    STG(nb, 1, 0, kn);
    BAR;
    MM(acc[1][0], k1, q0);
    // ph4
    STG(nb, 1, 1, kn);
    VM2; BAR;
    MM(acc[1][1], k1, q1);
  }
#undef STG

  asm volatile("s_waitcnt vmcnt(0)" ::: "memory");
  __syncthreads();

  const float K2c = 0.04419417382415922f * 1.4426950408889634f;  // 1/sqrt(512)*log2e
#pragma unroll
  for (int qh = 0; qh < 2; qh++)
#pragma unroll
    for (int n = 0; n < 2; n++) {
      int qr = qh * 128 + wn4 * 32 + n * 16 + r;
      float s = 0.f;
#pragma unroll
      for (int kh = 0; kh < 2; kh++)
#pragma unroll
        for (int m = 0; m < 4; m++) {
          f32x4 a = acc[kh][qh][m][n];
          float v0 = __builtin_amdgcn_exp2f(a[0] * K2c);
          float v1 = __builtin_amdgcn_exp2f(a[1] * K2c);
          float v2 = __builtin_amdgcn_exp2f(a[2] * K2c);
          float v3 = __builtin_amdgcn_exp2f(a[3] * K2c);
          s += (v0 + v1) + (v2 + v3);
          uint2 pk; pk.x = cvtpk(v0, v1); pk.y = cvtpk(v2, v3);
          int ke = kh * 128 + wm2 * 64 + m * 16 + g * 4;
          int el = qr * 256 + (ke ^ ((qr & 7) * 8));
          *(uint2*)&smem[el] = pk;
        }
      s += __shfl_xor(s, 16);
      s += __shfl_xor(s, 32);
      if (g == 0)
        lpart[(size_t)((bcol >> 7) + wm2) * 8192 + brow + qr] = s;
    }
  __syncthreads();
#pragma unroll
  for (int jj = 0; jj < 16; jj++) {
    int row = jj * 16 + (tid >> 5);
    int g32 = tid & 31;
    uint4 v = *(const uint4*)&smem[row * 256 + ((g32 ^ (row & 7)) * 8)];
    *(uint4*)&U[(size_t)(brow + row) * 8192 + bcol + g32 * 8] = v;
  }
}

// ================= 256x256 PV-GEMM (r13 schedule), split-K=4, bf16 partials =========
__global__ __launch_bounds__(512, 2) void gemm256_pv_kernel(
    const unsigned short* __restrict__ Uu, const unsigned short* __restrict__ VT,
    unsigned short* __restrict__ P0, unsigned short* __restrict__ P1,
    unsigned short* __restrict__ P2, unsigned short* __restrict__ P3) {
  __shared__ __align__(16) unsigned short smem[65536];
  const int tid = threadIdx.x, lane = tid & 63;
  const int w = tid >> 6;
  const int g = lane >> 4, r = lane & 15;
  const int wm2 = w & 1, wn4 = w >> 1;
  const int c = blockIdx.x & 7;
  const int hi = blockIdx.x >> 3;
  const int nt = hi & 1, qthi = hi >> 1;
  const int qlo = c >> 2, kz = c & 3;
  const int qt = qthi * 2 + qlo;
  const int brow = qt * 256;
  const int bcol = nt * 256;
  const int koff = kz * 2048;
  const int srow = tid >> 3;
  const int sg = tid & 7;
  unsigned short* P = (kz == 0) ? P0 : (kz == 1) ? P1 : (kz == 2) ? P2 : P3;

  f32x4 acc[2][2][4][2] = {};             // [dh][qh][m][n]

#define STGP(b, a, h, kt)                                                                        \
  do {                                                                                           \
    const unsigned short* _src = (a) ? VT : Uu;                                                  \
    int _base = (a) ? bcol : brow;                                                               \
    int _r0 = (h) * 128 + srow;                                                                  \
    int _r1 = _r0 + 64;                                                                          \
    unsigned short* _d = smem + (b) * 32768 + (a) * 16384 + (h) * 8192 + tid * 8;                \
    gll16(_src + (size_t)(_base + _r0) * 8192 + koff + (kt) * 64 + ((sg ^ (_r0 & 7)) * 8), _d);  \
    gll16(_src + (size_t)(_base + _r1) * 8192 + koff + (kt) * 64 + ((sg ^ (_r1 & 7)) * 8),       \
          _d + 4096);                                                                            \
  } while (0)

  auto LDV = [&](sh8 (&vf)[2][4], int B_, int dh) {
    const unsigned short* Bs = smem + B_ * 32768 + 16384;
#pragma unroll
    for (int kk = 0; kk < 2; kk++)
#pragma unroll
      for (int m = 0; m < 4; m++) {
        int row = dh * 128 + wm2 * 64 + m * 16 + r;
        vf[kk][m] = *(const sh8*)&Bs[row * 64 + (((kk * 4 + g) ^ (r & 7)) * 8)];
      }
  };
  auto LDU = [&](sh8 (&uf)[2][2], int B_, int qh) {
    const unsigned short* As = smem + B_ * 32768;
#pragma unroll
    for (int kk = 0; kk < 2; kk++)
#pragma unroll
      for (int n = 0; n < 2; n++) {
        int row = qh * 128 + wn4 * 32 + n * 16 + r;
        uf[kk][n] = *(const sh8*)&As[row * 64 + (((kk * 4 + g) ^ (r & 7)) * 8)];
      }
  };
  auto MM = [&](f32x4 (&cc)[4][2], sh8 (&vf)[2][4], sh8 (&uf)[2][2]) {
    __builtin_amdgcn_s_setprio(1);
#pragma unroll
    for (int kk = 0; kk < 2; kk++)
#pragma unroll
      for (int m = 0; m < 4; m++)
#pragma unroll
        for (int n = 0; n < 2; n++)
          cc[m][n] = mfma16(vf[kk][m], uf[kk][n], cc[m][n]);
    __builtin_amdgcn_s_setprio(0);
  };

  STGP(0, 0, 0, 0); STGP(0, 0, 1, 0); STGP(0, 1, 0, 0); STGP(0, 1, 1, 0);
  asm volatile("s_waitcnt vmcnt(0)" ::: "memory");
  BAR;

#pragma unroll 2
  for (int kt = 0; kt < 32; ++kt) {
    const int cur = kt & 1, nb = cur ^ 1;
    const int kn = (kt < 31) ? kt + 1 : 31;
    sh8 v0[2][4], v1[2][4], u0[2][2], u1[2][2];
    // ph1
    LDV(v0, cur, 0); LDU(u0, cur, 0);
    STGP(nb, 0, 0, kn);
    VM2; BAR;
    MM(acc[0][0], v0, u0);
    // ph2
    LDU(u1, cur, 1);
    STGP(nb, 0, 1, kn);
    BAR;
    MM(acc[0][1], v0, u1);
    // ph3
    LDV(v1, cur, 1);
    STGP(nb, 1, 0, kn);
    BAR;
    MM(acc[1][0], v1, u0);
    // ph4
    STGP(nb, 1, 1, kn);
    VM2; BAR;
    MM(acc[1][1], v1, u1);
  }
#undef STGP
#undef BAR
#undef VM2

  asm volatile("s_waitcnt vmcnt(0)" ::: "memory");
  __syncthreads();

  // epilogue: bf16 restage (swizzled) + coalesced 512B-row stores to partial
#pragma unroll
  for (int qh = 0; qh < 2; qh++)
#pragma unroll
    for (int n = 0; n < 2; n++) {
      int qr = qh * 128 + wn4 * 32 + n * 16 + r;
#pragma unroll
      for (int dh = 0; dh < 2; dh++)
#pragma unroll
        for (int m = 0; m < 4; m++) {
          f32x4 a = acc[dh][qh][m][n];
          uint2 pk; pk.x = cvtpk(a[0], a[1]); pk.y = cvtpk(a[2], a[3]);
          int de = dh * 128 + wm2 * 64 + m * 16 + g * 4;
          int el = qr * 256 + (de ^ ((qr & 7) * 8));
          *(uint2*)&smem[el] = pk;
        }
    }
  __syncthreads();
#pragma unroll
  for (int jj = 0; jj < 16; jj++) {
    int row = jj * 16 + (tid >> 5);
    int g32 = tid & 31;
    uint4 v = *(const uint4*)&smem[row * 256 + ((g32 ^ (row & 7)) * 8)];
    *(uint4*)&P[(size_t)(brow + row) * 512 + bcol + g32 * 8] = v;
  }
}

// ---------- 128x128 GEMM core (BK=64, dbuf + counted vmcnt) ----------
// MODE 0: fp32 direct store (+bias). MODE 1: bf16 LDS-coalesced store (+bias);
// transp=true writes the tile transposed (fused V^T).
template <int MODE>
DEV void gemm_core(const unsigned short* __restrict__ A, int lda,
                   const unsigned short* __restrict__ Bt, int ldb,
                   const float* __restrict__ bias, void* __restrict__ Cv, int ldc,
                   int kSteps, int koff, int brow, int bcol,
                   unsigned short* smem, bool transp) {
  const int tid = threadIdx.x, lane = tid & 63, w = tid >> 6;
  const int g = lane >> 4, r = lane & 15;
  const int wr = w >> 1, wc = w & 1;
  const int rA = w * 8 + (lane >> 3);
  const int sgl = lane & 7;
  const int scol = ((sgl ^ (lane >> 3)) * 8);
  const unsigned short* aP = A + (size_t)(brow + rA) * lda + koff + scol;
  const unsigned short* bP = Bt + (size_t)(bcol + rA) * ldb + koff + scol;
  const int lOff = rA * 64 + sgl * 8;
  f32x4 acc[4][4] = {};
  const int fr = r & 7;

  auto STAGE = [&](int buf, int ks) {
    unsigned short* lA = smem + buf * 16384 + lOff;
    unsigned short* lB = smem + buf * 16384 + 8192 + lOff;
    const size_t ko = (size_t)ks * 64;
#pragma unroll
    for (int cc = 0; cc < 4; cc++) gll16(aP + (size_t)cc * 32 * lda + ko, lA + cc * 32 * 64);
#pragma unroll
    for (int cc = 0; cc < 4; cc++) gll16(bP + (size_t)cc * 32 * ldb + ko, lB + cc * 32 * 64);
  };
  auto COMPUTE = [&](int buf) {
    const unsigned short* As = smem + buf * 16384;
    const unsigned short* Bs = As + 8192;
#pragma unroll
    for (int kk = 0; kk < 2; kk++) {
      sh8 af[4], bfr[4];
#pragma unroll
      for (int m = 0; m < 4; m++)
        af[m] = *(const sh8*)&As[(wr * 64 + m * 16 + r) * 64 + (((kk * 4 + g) ^ fr) * 8)];
#pragma unroll
      for (int n = 0; n < 4; n++)
        bfr[n] = *(const sh8*)&Bs[(wc * 64 + n * 16 + r) * 64 + (((kk * 4 + g) ^ fr) * 8)];
#pragma unroll
      for (int m = 0; m < 4; m++)
#pragma unroll
        for (int n = 0; n < 4; n++) acc[m][n] = mfma16(af[m], bfr[n], acc[m][n]);
    }
  };

  STAGE(0, 0);
  int cur = 0;
  for (int ks = 0; ks + 1 < kSteps; ks++) {
    STAGE(cur ^ 1, ks + 1);
    asm volatile("s_waitcnt vmcnt(8)" ::: "memory");
    asm volatile("s_barrier" ::: "memory");
    COMPUTE(cur);
    asm volatile("s_barrier" ::: "memory");
    cur ^= 1;
  }
  asm volatile("s_waitcnt vmcnt(0)" ::: "memory");
  asm volatile("s_barrier" ::: "memory");
  COMPUTE(cur);

  if (MODE == 0) {
#pragma unroll
    for (int n = 0; n < 4; n++) {
      int col = bcol + wc * 64 + n * 16 + r;
      float bv = bias ? bias[col] : 0.f;
#pragma unroll
      for (int m = 0; m < 4; m++) {
        int row = brow + wr * 64 + m * 16 + g * 4;
#pragma unroll
        for (int i = 0; i < 4; i++)
          ((float*)Cv)[(size_t)(row + i) * ldc + col] = acc[m][n][i] + bv;
      }
    }
  } else {
    __syncthreads();
    if (!transp) {
#pragma unroll
      for (int m = 0; m < 4; m++) {
#pragma unroll
        for (int n = 0; n < 4; n++) {
          int coll = wc * 64 + n * 16 + r;
          float bv = bias ? bias[bcol + coll] : 0.f;
          int rb = (wr * 64 + m * 16 + g * 4) * 132 + coll;
          smem[rb] = f2bf(acc[m][n][0] + bv);
          smem[rb + 132] = f2bf(acc[m][n][1] + bv);
          smem[rb + 264] = f2bf(acc[m][n][2] + bv);
          smem[rb + 396] = f2bf(acc[m][n][3] + bv);
        }
      }
      __syncthreads();
      unsigned short* C = (unsigned short*)Cv;
#pragma unroll
      for (int jj = 0; jj < 8; jj++) {
        int row = w * 32 + jj * 4 + (lane >> 4);
        int colb = (lane & 15) * 8;
        uint4 v = *(const uint4*)&smem[row * 132 + colb];
        *(uint4*)&C[(size_t)(brow + row) * ldc + bcol + colb] = v;
      }
    } else {
      // transposed write: smem[col][row], then coalesced rows of C^T
#pragma unroll
      for (int m = 0; m < 4; m++) {
#pragma unroll
        for (int n = 0; n < 4; n++) {
          int coll = wc * 64 + n * 16 + r;
          float bv = bias ? bias[bcol + coll] : 0.f;
          int qrow = wr * 64 + m * 16 + g * 4;
          uint2 pk;
          pk.x = cvtpk(acc[m][n][0] + bv, acc[m][n][1] + bv);
          pk.y = cvtpk(acc[m][n][2] + bv, acc[m][n][3] + bv);
          *(uint2*)&smem[coll * 132 + qrow] = pk;
        }
      }
      __syncthreads();
      unsigned short* C = (unsigned short*)Cv;
#pragma unroll
      for (int jj = 0; jj < 8; jj++) {
        int hrow = w * 32 + jj * 4 + (lane >> 4);
        int nb8 = (lane & 15) * 8;
        uint4 v = *(const uint4*)&smem[hrow * 132 + nb8];
        *(uint4*)&C[(size_t)(bcol + hrow) * ldc + brow + nb8] = v;
      }
    }
  }
}

// ---------- GEMM wrappers ----------
__global__ __launch_bounds__(256, 2) void gemm_qkv_kernel(
    const unsigned short* __restrict__ A,
    const unsigned short* __restrict__ B0, const unsigned short* __restrict__ B1,
    const unsigned short* __restrict__ B2,
    const float* __restrict__ c0, const float* __restrict__ c1, const float* __restrict__ c2,
    unsigned short* __restrict__ C0, unsigned short* __restrict__ C1,
    unsigned short* __restrict__ CT2) {
  __shared__ __align__(16) unsigned short smem[32768];
  const unsigned short* Bt; const float* bias; unsigned short* C;
  bool tr; int ldc;
  switch (blockIdx.z) {
    case 0: Bt = B0; bias = c0; C = C0; tr = false; ldc = 512; break;
    case 1: Bt = B1; bias = c1; C = C1; tr = false; ldc = 512; break;
    default: Bt = B2; bias = c2; C = CT2; tr = true; ldc = 8192; break;  // V -> vtb^T
  }
  gemm_core<1>(A, 512, Bt, 512, bias, C, ldc, 8, 0,
               blockIdx.x * 128, blockIdx.y * 128, smem, tr);
}

__global__ __launch_bounds__(256, 2) void gemm_o_kernel(
    const unsigned short* __restrict__ att, const unsigned short* __restrict__ woT,
    const float* __restrict__ bo, float* __restrict__ out) {
  __shared__ __align__(16) unsigned short smem[32768];
  gemm_core<0>(att, 512, woT, 512, bo, out, 512, 8, 0,
               blockIdx.x * 128, blockIdx.y * 128, smem, false);
}

// ---------- combine row-sum partials (64 k-chunks) -> 1/l ----------
__global__ void combine_l_kernel(const float* __restrict__ lpart, float* __restrict__ linv) {
  int row = blockIdx.x * 256 + threadIdx.x;
  float s = 0.f;
#pragma unroll 8
  for (int j = 0; j < 64; j++) s += lpart[(size_t)j * 8192 + row];
  linv[row] = 1.0f / s;
}

// ---------- add four bf16 partials * linv[row] -> bf16 ----------
__global__ void addcvt4_kernel(const unsigned short* __restrict__ p0,
                               const unsigned short* __restrict__ p1,
                               const unsigned short* __restrict__ p2,
                               const unsigned short* __restrict__ p3,
                               const float* __restrict__ linv,
                               unsigned short* __restrict__ o, int n8) {
  int i = blockIdx.x * blockDim.x + threadIdx.x;
  int stride = gridDim.x * blockDim.x;
  for (; i < n8; i += stride) {
    float inv = linv[i >> 6];
    uint4 a = ((const uint4*)p0)[i];
    uint4 b = ((const uint4*)p1)[i];
    uint4 c = ((const uint4*)p2)[i];
    uint4 d = ((const uint4*)p3)[i];
    const unsigned* ua = (const unsigned*)&a;
    const unsigned* ub = (const unsigned*)&b;
    const unsigned* uc = (const unsigned*)&c;
    const unsigned* ud = (const unsigned*)&d;
    unsigned out[4];
#pragma unroll
    for (int e = 0; e < 4; e++) {
      float lo = __uint_as_float(ua[e] << 16) + __uint_as_float(ub[e] << 16) +
                 __uint_as_float(uc[e] << 16) + __uint_as_float(ud[e] << 16);
      float hi = __uint_as_float(ua[e] & 0xffff0000u) + __uint_as_float(ub[e] & 0xffff0000u) +
                 __uint_as_float(uc[e] & 0xffff0000u) + __uint_as_float(ud[e] & 0xffff0000u);
      out[e] = cvtpk(lo * inv, hi * inv);
    }
    ((uint4*)o)[i] = *(uint4*)out;
  }
}

// ---------- launch ----------
extern "C" void kernel_launch(void* const* d_in, const int* in_sizes, int n_in,
                              void* d_out, int out_size, void* d_ws, size_t ws_size,
                              hipStream_t stream) {
  const float* x  = (const float*)d_in[0];
  const float* Wq = (const float*)d_in[1];
  const float* bq = (const float*)d_in[2];
  const float* Wk = (const float*)d_in[3];
  const float* bk = (const float*)d_in[4];
  const float* Wv = (const float*)d_in[5];
  const float* bv = (const float*)d_in[6];
  const float* Wo = (const float*)d_in[7];
  const float* bo = (const float*)d_in[8];
  char* ws = (char*)d_ws;

  unsigned short* U   = (unsigned short*)(ws + 0);          // 134.2 MB
  unsigned short* xb  = (unsigned short*)(ws + 0);          // overlay (dead after QKV)
  unsigned short* att = (unsigned short*)(ws + 0);          // overlay (after PV)
  unsigned short* qb  = (unsigned short*)(ws + 134217728);
  unsigned short* kb  = (unsigned short*)(ws + 142606336);
  unsigned short* vtb = (unsigned short*)(ws + 150994944);
  unsigned short* wqT = (unsigned short*)(ws + 159383552);
  unsigned short* wkT = (unsigned short*)(ws + 159907840);
  unsigned short* wvT = (unsigned short*)(ws + 160432128);
  unsigned short* woT = (unsigned short*)(ws + 160956416);
  float* lpart = (float*)(ws + 161480704);                  // 2 MB [64][8192]
  float* linv  = (float*)(ws + 165675008);                  // 32 KB
  unsigned short* P0 = qb;
  unsigned short* P1 = kb;
  unsigned short* P2 = (unsigned short*)d_out;
  unsigned short* P3 = (unsigned short*)d_out + 4194304;

  cvt_x_kernel<<<2048, 256, 0, stream>>>(x, xb, 8192 * 512 / 4);
  cvt_wT_kernel<<<dim3(16, 16, 4), 256, 0, stream>>>(Wq, Wk, Wv, Wo, wqT, wkT, wvT, woT);
  gemm_qkv_kernel<<<dim3(64, 4, 3), 256, 0, stream>>>(
      xb, wqT, wkT, wvT, bq, bk, bv, qb, kb, vtb);
  gemm256_u_kernel<<<1024, 512, 0, stream>>>(qb, kb, U, lpart);
  combine_l_kernel<<<32, 256, 0, stream>>>(lpart, linv);
  gemm256_pv_kernel<<<256, 512, 0, stream>>>(U, vtb, P0, P1, P2, P3);
  addcvt4_kernel<<<2048, 256, 0, stream>>>(P0, P1, P2, P3, linv, att, 8192 * 512 / 8);
  gemm_o_kernel<<<dim3(64, 4), 256, 0, stream>>>(att, woT, bo, (float*)d_out);
}